// Round 12
// baseline (359.358 us; speedup 1.0000x reference)
//
#include <hip/hip_runtime.h>

// CTC-like forward scan. R12: single kernel, single wave per batch element.
// R10/R11 post-mortem: compiler defeats every source-level prefetch (sinks or
// rematerializes LDS/global loads to use sites -> ~120cy exposed latency per
// step; R11's VGPR_Count=60 proves the 64-VGPR window never existed). Fix:
// window loads are inline-asm ds_read_b128 with "=v" outputs (cannot be sunk
// or rematerialized; results pinned in VGPRs), each burst asm carries
// s_waitcnt lgkmcnt(8) and takes the consuming window's regs as "+v" so no
// use schedules before the wait. Prefetch distance = 1 window (~400cy).
// The whole b-strip (4096 rows x 16B = 64KB) lives in LDS, exp+packed by an
// in-kernel prologue (kills the separate prepass kernel and its ~55us
// launch+traffic overhead). Numerics verbatim R9-R11 (absmax 9.77e-4):
// packed bf16 V + f32 S rows, v_perm selects, per-lane exponent frames with
// down-only alignment, renorm every 8 steps, boundary via DPP wave_shr:1.

#define TT 4096
#define BB 64
#define PP 512
#define LN2F 0.69314718055994531f

typedef unsigned uv4 __attribute__((ext_vector_type(4)));
typedef __attribute__((address_space(3))) const uv4* ldsrow_t;

__device__ __forceinline__ unsigned bf16_rne(float f) {
    unsigned u = __float_as_uint(f);
    return (u + 0x7FFFu + ((u >> 16) & 1u)) >> 16;
}

// lane n <- lane n-1 across the whole wave; lane 0 keeps old (overridden).
__device__ __forceinline__ int shl1w_i(int s) {
    return __builtin_amdgcn_update_dpp(s, s, 0x138 /*wave_shr:1*/, 0xF, 0xF, false);
}
__device__ __forceinline__ float shl1w_f(float s) {
    return __int_as_float(shl1w_i(__float_as_int(s)));
}

// Burst-load 8 rows for the NEXT window into N0..N7 and wait until the
// CURRENT window's rows (C0..C7, loaded by the previous burst) are resident.
// "+v" on C* forces every consumer of the current window after this asm.
#define BURST(N0,N1,N2,N3,N4,N5,N6,N7,C0,C1,C2,C3,C4,C5,C6,C7,AP)            \
    asm volatile("ds_read_b128 %0, %16 offset:0\n\t"                          \
                 "ds_read_b128 %1, %16 offset:16\n\t"                         \
                 "ds_read_b128 %2, %16 offset:32\n\t"                         \
                 "ds_read_b128 %3, %16 offset:48\n\t"                         \
                 "ds_read_b128 %4, %16 offset:64\n\t"                         \
                 "ds_read_b128 %5, %16 offset:80\n\t"                         \
                 "ds_read_b128 %6, %16 offset:96\n\t"                         \
                 "ds_read_b128 %7, %16 offset:112\n\t"                        \
                 "s_waitcnt lgkmcnt(8)"                                       \
                 : "=v"(N0), "=v"(N1), "=v"(N2), "=v"(N3),                    \
                   "=v"(N4), "=v"(N5), "=v"(N6), "=v"(N7),                    \
                   "+v"(C0), "+v"(C1), "+v"(C2), "+v"(C3),                    \
                   "+v"(C4), "+v"(C5), "+v"(C6), "+v"(C7)                     \
                 : "v"(AP))

__global__ __launch_bounds__(64, 1)
void ctc_scan(const float* __restrict__ x, const int* __restrict__ seqs,
              const int* __restrict__ seqlens, float* __restrict__ out) {
    __shared__ __align__(16) uv4 xrow[TT];         // 64 KB packed rows
    __shared__ float garr[PP + 1];

    const int b = blockIdx.x;
    const int l = threadIdx.x;                     // 0..63
    const bool lane0 = (l == 0);

    // per-lane v_perm byte controls (validated R9-R11 convention)
    unsigned ctrl0, ctrl1, ctrl2, ctrl3;
    {
        unsigned c[4];
#pragma unroll
        for (int k = 0; k < 4; ++k) {
            unsigned i0 = (unsigned)seqs[b * PP + 8 * l + 2 * k];
            unsigned i1 = (unsigned)seqs[b * PP + 8 * l + 2 * k + 1];
            c[k] = (2 * i0) | ((2 * i0 + 1) << 8) | ((2 * i1) << 16) | ((2 * i1 + 1) << 24);
        }
        ctrl0 = c[0]; ctrl1 = c[1]; ctrl2 = c[2]; ctrl3 = c[3];
    }

    // ---- prologue: exp+pack this block's strip into LDS (lane l: t=i*64+l) ----
#pragma unroll 4
    for (int i = 0; i < 64; ++i) {
        const int t = i * 64 + l;
        const float* r = x + ((size_t)t * BB + b) * 5;
        float a0 = r[0], a1 = r[1], a2 = r[2], a3 = r[3], a4 = r[4];
        uv4 o;
        o[0] = bf16_rne(__expf(a0)) | (bf16_rne(__expf(a1)) << 16);
        o[1] = bf16_rne(__expf(a2)) | (bf16_rne(__expf(a3)) << 16);
        o[2] = __float_as_uint(__expf(a4));
        o[3] = 0u;
        xrow[t] = o;
    }
    __syncthreads();

    const ldsrow_t lrow = (ldsrow_t)(uintptr_t)&xrow[0];

    float F[8];
#pragma unroll
    for (int i = 0; i < 8; ++i) F[i] = 0.0f;
    float F0 = lane0 ? 1.0f : 0.0f;
    int M = 0, M0 = 0;
    float sAx = 1.0f;

    uv4 A0, A1, A2, A3, A4, A5, A6, A7;
    uv4 B0, B1, B2, B3, B4, B5, B6, B7;

    // prologue burst: window 0 into A, drain fully
    asm volatile("ds_read_b128 %0, %8 offset:0\n\t"
                 "ds_read_b128 %1, %8 offset:16\n\t"
                 "ds_read_b128 %2, %8 offset:32\n\t"
                 "ds_read_b128 %3, %8 offset:48\n\t"
                 "ds_read_b128 %4, %8 offset:64\n\t"
                 "ds_read_b128 %5, %8 offset:80\n\t"
                 "ds_read_b128 %6, %8 offset:96\n\t"
                 "ds_read_b128 %7, %8 offset:112\n\t"
                 "s_waitcnt lgkmcnt(0)"
                 : "=v"(A0), "=v"(A1), "=v"(A2), "=v"(A3),
                   "=v"(A4), "=v"(A5), "=v"(A6), "=v"(A7)
                 : "v"(lrow));

    auto bookkeep = [&]() {
        float m = F[0];
#pragma unroll
        for (int i = 1; i < 8; ++i) m = fmaxf(m, F[i]);
        int e2 = ((__float_as_int(m) >> 23) & 0xFF) - 127;
        e2 = (m > 0.0f) ? e2 : 0;
        const int Mp = M + e2;                     // post-renorm frame
        const int Mlp = shl1w_i(Mp);               // neighbor's post-renorm frame
        int e0 = ((__float_as_int(F0) >> 23) & 0xFF) - 127;
        e0 = (F0 > 0.0f) ? e0 : 0;
        F0 = ldexpf(F0, -e0);
        M0 += e0;
        int dl = lane0 ? (M0 - Mp) : (Mlp - Mp);
        int dlc = dl > 0 ? dl : 0;                 // down-only self-squash
        const int Mnew = Mp + dlc;
        const int sh = Mnew - M;
#pragma unroll
        for (int i = 0; i < 8; ++i) F[i] = ldexpf(F[i], -sh);
        M = Mnew;
        int dn = Mlp - M; dn = dn > 0 ? 0 : dn;
        int d0 = M0 - M;  d0 = d0 > 0 ? 0 : d0;
        const float sA  = ldexpf(1.0f, dn);
        const float sF0 = ldexpf(1.0f, d0);
        sAx = lane0 ? sF0 : sA;
    };

#define STEP(ROW)                                                             \
    do {                                                                      \
        const float S = __uint_as_float((ROW)[2]);                            \
        unsigned p0 = __builtin_amdgcn_perm((ROW)[1], (ROW)[0], ctrl0);       \
        unsigned p1 = __builtin_amdgcn_perm((ROW)[1], (ROW)[0], ctrl1);       \
        unsigned p2 = __builtin_amdgcn_perm((ROW)[1], (ROW)[0], ctrl2);       \
        unsigned p3 = __builtin_amdgcn_perm((ROW)[1], (ROW)[0], ctrl3);       \
        const float V0 = __uint_as_float(p0 << 16);                           \
        const float V1 = __uint_as_float(p0 & 0xFFFF0000u);                   \
        const float V2 = __uint_as_float(p1 << 16);                           \
        const float V3 = __uint_as_float(p1 & 0xFFFF0000u);                   \
        const float V4 = __uint_as_float(p2 << 16);                           \
        const float V5 = __uint_as_float(p2 & 0xFFFF0000u);                   \
        const float V6 = __uint_as_float(p3 << 16);                           \
        const float V7 = __uint_as_float(p3 & 0xFFFF0000u);                   \
        const float Flr = shl1w_f(F[7]);                                      \
        const float fin = (lane0 ? F0 : Flr) * sAx;                           \
        F[7] = fmaf(F[7], S, F[6] * V7);                                      \
        F[6] = fmaf(F[6], S, F[5] * V6);                                      \
        F[5] = fmaf(F[5], S, F[4] * V5);                                      \
        F[4] = fmaf(F[4], S, F[3] * V4);                                      \
        F[3] = fmaf(F[3], S, F[2] * V3);                                      \
        F[2] = fmaf(F[2], S, F[1] * V2);                                      \
        F[1] = fmaf(F[1], S, F[0] * V1);                                      \
        F[0] = fmaf(F[0], S, fin * V0);                                       \
        F0 *= S;                                                              \
    } while (0)

#pragma unroll 1
    for (int w = 0; w < 512; w += 2) {
        // window w (consume A), burst w+1 into B
        {
            const int wn = w + 1;
            BURST(B0,B1,B2,B3,B4,B5,B6,B7, A0,A1,A2,A3,A4,A5,A6,A7, lrow + wn * 8);
            bookkeep();
            STEP(A0); STEP(A1); STEP(A2); STEP(A3);
            STEP(A4); STEP(A5); STEP(A6); STEP(A7);
        }
        // window w+1 (consume B), burst w+2 into A (clamped on last)
        {
            const int wn = (w + 2 > 511) ? 511 : (w + 2);
            BURST(A0,A1,A2,A3,A4,A5,A6,A7, B0,B1,B2,B3,B4,B5,B6,B7, lrow + wn * 8);
            bookkeep();
            STEP(B0); STEP(B1); STEP(B2); STEP(B3);
            STEP(B4); STEP(B5); STEP(B6); STEP(B7);
        }
    }
#undef STEP

    // ---- epilogue: log2 reconstruction (denormal-safe) ----
#pragma unroll
    for (int i = 0; i < 8; ++i) {
        float v = fmaxf(F[i] * 16777216.0f, 1e-38f);
        garr[8 * l + 1 + i] = __log2f(v) - 24.0f + (float)M;
    }
    if (lane0) {
        float v0 = fmaxf(F0 * 16777216.0f, 1e-38f);
        garr[0] = __log2f(v0) - 24.0f + (float)M0;
    }
    __syncthreads();
    if (lane0) {
        const int sl = seqlens[b];
        out[b] = -(garr[sl] * LN2F) / (float)TT;
    }
}

extern "C" void kernel_launch(void* const* d_in, const int* in_sizes, int n_in,
                              void* d_out, int out_size, void* d_ws, size_t ws_size,
                              hipStream_t stream) {
    const float* x       = (const float*)d_in[0];
    const int*   seqs    = (const int*)d_in[1];
    const int*   seqlens = (const int*)d_in[2];
    float*       out     = (float*)d_out;

    ctc_scan<<<BB, 64, 0, stream>>>(x, seqs, seqlens, out);
}